// Round 12
// baseline (121.118 us; speedup 1.0000x reference)
//
#include <hip/hip_runtime.h>
#include <hip/hip_bf16.h>

#define CDIM   64
#define HWDIM  4096
#define NCODES 1024
#define NELEM  8388608   // 32*64*64*64 = N*C
#define NBLOCK 256       // vq_main grid: one block per CU, 512 rows each
#define NPART  (NBLOCK * 8)
#define LDSSZ  (131072 + 16 * 68 * 4)   // 128 KB codebook + padded bias

typedef short bf16x8 __attribute__((ext_vector_type(8)));
typedef float f32x4  __attribute__((ext_vector_type(4)));

__device__ __forceinline__ unsigned short f2bf(float f) {
    union { float f; unsigned u; } v; v.f = f;
    unsigned r = v.u + 0x7fffu + ((v.u >> 16) & 1u);   // round-to-nearest-even
    return (unsigned short)(r >> 16);
}
__device__ __forceinline__ unsigned asu(float f) {
    union { float f; unsigned u; } v; v.f = f; return v.u;
}
__device__ __forceinline__ float asf(unsigned u) {
    union { unsigned u; float f; } v; v.u = u; return v.f;
}
__device__ __forceinline__ void gload_lds16(const void* g, void* l) {
    __builtin_amdgcn_global_load_lds(
        (const __attribute__((address_space(1))) void*)g,
        (__attribute__((address_space(3))) void*)l, 16, 0, 0);
}

// Vectorized prep: bf16 codebook + (-0.5*||e||^2) bias; zero the done-counter.
__global__ void vq_prep(const float* __restrict__ E,
                        unsigned short* __restrict__ Eb,
                        float* __restrict__ bias05,
                        int* __restrict__ cnt) {
    int t = blockIdx.x * blockDim.x + threadIdx.x;   // one thread per code
    if (t == 0) *cnt = 0;
    if (t < NCODES) {
        const float4* ev = (const float4*)(E + t * CDIM);
        float s = 0.f;
        unsigned short u[CDIM];
        #pragma unroll
        for (int i = 0; i < 16; ++i) {
            float4 v = ev[i];
            s = fmaf(v.x, v.x, s); s = fmaf(v.y, v.y, s);
            s = fmaf(v.z, v.z, s); s = fmaf(v.w, v.w, s);
            u[4*i+0] = f2bf(v.x); u[4*i+1] = f2bf(v.y);
            u[4*i+2] = f2bf(v.z); u[4*i+3] = f2bf(v.w);
        }
        #pragma unroll
        for (int k = 0; k < 8; ++k) {
            bf16x8 w;
            #pragma unroll
            for (int j = 0; j < 8; ++j) w[j] = (short)u[8*k+j];
            *(bf16x8*)(Eb + t * CDIM + k * 8) = w;
        }
        bias05[t] = -0.5f * s;
    }
}

// One block per CU: 512 thr = 8 waves x 64 rows (halves per-CU LDS-read
// amplification vs 16x32). Full codebook (128 KB swizzled) + transposed bias
// in dynamic LDS via async global_load_lds; ONE barrier; K-loop addressing
// fully hoisted (ds_read_b128 with immediate offsets). Loss finished by the
// LAST block (device-scope fence + atomic counter; fixed-order sum).
__global__ __launch_bounds__(512)
void vq_main(const float* __restrict__ z,
             const float* __restrict__ E,
             const unsigned short* __restrict__ Eb,
             const float* __restrict__ bias05,
             float* __restrict__ out,
             float* __restrict__ partial,
             int* __restrict__ cnt) {
    extern __shared__ char smem[];
    unsigned short* sEb = (unsigned short*)smem;           // 128 KB swizzled
    float (*sBiasT)[68] = (float(*)[68])(smem + 131072);   // [16][68] padded
    __shared__ int amLast;

    const int lane = threadIdx.x & 63;
    const int wave = threadIdx.x >> 6;   // 0..7
    const int lrow = lane & 15;          // row/code-col within 16-tile
    const int lgrp = lane >> 4;          // k-group 0..3

    const int n0 = blockIdx.x * 512 + wave * 64;  // wave's first flat row
    const int b  = n0 >> 12;
    const int hw = n0 & 4095;            // 64-aligned; +63 stays in batch
    const float* zb   = z   + (size_t)b * (CDIM * HWDIM);
    float*       outb = out + (size_t)b * (CDIM * HWDIM);

    // ---- stage full codebook via async DMA (linear LDS dest, inverse-
    // swizzled per-lane global source). 8192 chunks of 16 B = 128 KB.
    #pragma unroll
    for (int i = 0; i < 16; ++i) {
        const int c   = i * 512 + (int)threadIdx.x;    // chunk id 0..8191
        const int row = c >> 3;
        const int s   = c & 7;
        const unsigned short* g = Eb + row * CDIM + ((s ^ (row & 7)) << 3);
        gload_lds16(g, &sEb[c * 8]);
    }
    // bias, transposed: sBiasT[code&15][code>>4]
    if (threadIdx.x < NCODES) {
        const int i = threadIdx.x;
        sBiasT[i & 15][i >> 4] = bias05[i];
        if (threadIdx.x < NCODES - 512) {
            const int i2 = threadIdx.x + 512;
            sBiasT[i2 & 15][i2 >> 4] = bias05[i2];
        }
    }

    // A fragments: tile t rows n0+16t..+15. lane holds A[lrow][k=32s+8g+j].
    float szz = 0.f;
    bf16x8 afrag[4][2];
    #pragma unroll
    for (int t = 0; t < 4; ++t)
        #pragma unroll
        for (int s = 0; s < 2; ++s)
            #pragma unroll
            for (int j = 0; j < 8; ++j) {
                int c = 32 * s + 8 * lgrp + j;
                float v = zb[c * HWDIM + hw + t * 16 + lrow];
                szz = fmaf(v, v, szz);
                afrag[t][s][j] = (short)f2bf(v);
            }

    float run[4][4];
    #pragma unroll
    for (int t = 0; t < 4; ++t)
        #pragma unroll
        for (int r = 0; r < 4; ++r) run[t][r] = -3.0e38f;

    __syncthreads();   // the ONLY barrier: DMA + bias complete

    // loop-invariant swizzled addresses (rowh&7 == lrow&7 for all kt)
    const int s0byte = (lgrp ^ (lrow & 7)) << 4;
    const char* pa = (const char*)sEb + lrow * 128 + s0byte;
    const char* pb = (const char*)sEb + lrow * 128 + (s0byte ^ 64);
    const float* pbias = &sBiasT[lrow][0];
    unsigned codev = (unsigned)lrow;

    for (int ch = 0; ch < 8; ++ch) {
        f32x4 bq0 = *(const f32x4*)(pbias);       // biases kt = ch*8+0..3
        f32x4 bq1 = *(const f32x4*)(pbias + 4);   // biases kt = ch*8+4..7
        #pragma unroll
        for (int j = 0; j < 8; ++j) {
            bf16x8 b0 = *(const bf16x8*)(pa + j * 2048);
            bf16x8 b1 = *(const bf16x8*)(pb + j * 2048);
            const float bv = (j < 4) ? bq0[j] : bq1[j - 4];   // static idx
            f32x4 ci = {bv, bv, bv, bv};
            const unsigned code = codev + (unsigned)(j * 16);
            #pragma unroll
            for (int t = 0; t < 4; ++t) {
                f32x4 acc = __builtin_amdgcn_mfma_f32_16x16x32_bf16(afrag[t][0], b0, ci, 0, 0, 0);
                acc = __builtin_amdgcn_mfma_f32_16x16x32_bf16(afrag[t][1], b1, acc, 0, 0, 0);
                #pragma unroll
                for (int r = 0; r < 4; ++r) {
                    float key = asf((asu(acc[r]) & 0xFFFFFC00u) | code);
                    run[t][r] = fmaxf(run[t][r], key);
                }
            }
        }
        pa += 16384; pb += 16384; pbias += 8; codev += 128;
    }

    // reduce packed keys across the 16 code-columns (lrow lanes): pure max
    #pragma unroll
    for (int m = 1; m <= 8; m <<= 1)
        #pragma unroll
        for (int t = 0; t < 4; ++t)
            #pragma unroll
            for (int r = 0; r < 4; ++r)
                run[t][r] = fmaxf(run[t][r], __shfl_xor(run[t][r], m, 64));

    // redistribute winners via shuffles: lane (lrow,lgrp) holds rows 4g+r;
    // epilogue thread needs row lrow of each tile.
    int idxe[4];
    #pragma unroll
    for (int t = 0; t < 4; ++t) {
        const int src = (lrow >> 2) << 4;   // a lane whose lgrp == lrow>>2
        float g0 = __shfl(run[t][0], src, 64);
        float g1 = __shfl(run[t][1], src, 64);
        float g2 = __shfl(run[t][2], src, 64);
        float g3 = __shfl(run[t][3], src, 64);
        float sel = (lrow & 2) ? ((lrow & 1) ? g3 : g2)
                               : ((lrow & 1) ? g1 : g0);
        idxe[t] = (int)(asu(sel) & 1023u);
    }

    // epilogue: gather fp32 codebook rows, write transposed out
    #pragma unroll
    for (int t = 0; t < 4; ++t) {
        const int idxr = idxe[t];
        const f32x4* ep  = (const f32x4*)(E + idxr * CDIM      + 8 * lgrp);
        const f32x4* ep2 = (const f32x4*)(E + idxr * CDIM + 32 + 8 * lgrp);
        f32x4 qa = ep[0], qb = ep[1], qc = ep2[0], qd = ep2[1];
        float* ob = outb + hw + t * 16 + lrow;
        #pragma unroll
        for (int j = 0; j < 4; ++j) {
            ob[(8 * lgrp + j)          * HWDIM] = qa[j];
            ob[(8 * lgrp + 4 + j)      * HWDIM] = qb[j];
            ob[(32 + 8 * lgrp + j)     * HWDIM] = qc[j];
            ob[(32 + 8 * lgrp + 4 + j) * HWDIM] = qd[j];
        }
    }

    // loss partial: sum z^2 + sum over rows of d_min (= -2 * packed score)
    float dsum = 0.f;
    #pragma unroll
    for (int t = 0; t < 4; ++t)
        #pragma unroll
        for (int r = 0; r < 4; ++r) dsum += run[t][r];
    float contrib = szz + ((lrow == 0) ? (-2.f * dsum) : 0.f);
    #pragma unroll
    for (int m = 32; m >= 1; m >>= 1) contrib += __shfl_xor(contrib, m, 64);
    if (lane == 0) partial[blockIdx.x * 8 + wave] = contrib;

    // ---- merged finisher: last block (device-scope) reduces all partials
    __threadfence();                       // release partial stores
    __syncthreads();                       // all waves fenced
    if (threadIdx.x == 0)
        amLast = (atomicAdd(cnt, 1) == NBLOCK - 1) ? 1 : 0;
    __syncthreads();
    if (amLast) {
        __threadfence();                   // acquire others' partials
        float s = 0.f;
        #pragma unroll
        for (int i = 0; i < NPART / 512; ++i)
            s += partial[i * 512 + threadIdx.x];
        #pragma unroll
        for (int m = 32; m >= 1; m >>= 1) s += __shfl_xor(s, m, 64);
        float* red = (float*)smem;         // codebook area is done
        if (lane == 0) red[wave] = s;
        __syncthreads();
        if (threadIdx.x == 0) {
            float tot = 0.f;
            #pragma unroll
            for (int w2 = 0; w2 < 8; ++w2) tot += red[w2];
            out[NELEM] = 1.25f * tot / (float)NELEM;
        }
    }
}

extern "C" void kernel_launch(void* const* d_in, const int* in_sizes, int n_in,
                              void* d_out, int out_size, void* d_ws, size_t ws_size,
                              hipStream_t stream) {
    const float* z = (const float*)d_in[0];
    const float* E = (const float*)d_in[1];
    float* out = (float*)d_out;

    unsigned short* Eb = (unsigned short*)d_ws;                     // 128 KB
    float* bias05      = (float*)((char*)d_ws + 131072);            // 4 KB
    float* partial     = (float*)((char*)d_ws + 131072 + 4096);     // 8 KB
    int*   cnt         = (int*)((char*)d_ws + 131072 + 4096 + 8192);

    // allow >64 KB dynamic LDS (host-side attribute; graph-capture safe)
    hipFuncSetAttribute((const void*)vq_main,
                        hipFuncAttributeMaxDynamicSharedMemorySize, LDSSZ);

    vq_prep<<<4, 256, 0, stream>>>(E, Eb, bias05, cnt);
    vq_main<<<NBLOCK, 512, LDSSZ, stream>>>(z, E, Eb, bias05, out, partial, cnt);
}

// Round 13
// 36.578 us; speedup vs baseline: 3.3113x; 3.3113x over previous
//
#include <hip/hip_runtime.h>
#include <hip/hip_bf16.h>

#define CDIM   64
#define HWDIM  4096
#define NCODES 1024
#define NELEM  8388608   // 32*64*64*64 = N*C
#define NBLOCK 256       // vq_main grid: one block per CU, 512 rows each
#define NPART  (NBLOCK * 16)
#define LDSSZ  (131072 + 16 * 68 * 4)   // 128 KB codebook + padded bias

typedef short bf16x8 __attribute__((ext_vector_type(8)));
typedef float f32x4  __attribute__((ext_vector_type(4)));

__device__ __forceinline__ unsigned short f2bf(float f) {
    union { float f; unsigned u; } v; v.f = f;
    unsigned r = v.u + 0x7fffu + ((v.u >> 16) & 1u);   // round-to-nearest-even
    return (unsigned short)(r >> 16);
}
__device__ __forceinline__ unsigned asu(float f) {
    union { float f; unsigned u; } v; v.f = f; return v.u;
}
__device__ __forceinline__ float asf(unsigned u) {
    union { unsigned u; float f; } v; v.u = u; return v.f;
}

// One block per CU (1024 thr = 16 waves x 32 rows). Codebook conversion is
// FUSED into staging: each block reads fp32 E (256 KB, L2-resident), converts
// to bf16 in-register, ds_write_b128 to the swizzled LDS layout (chunk k of
// row t -> slot k^(t&7); read side uses the same involution). Bias computed
// per-thread during conversion (same fma order as old prep -> identical
// rounding). ONE barrier; K-loop addressing fully hoisted (ds_read_b128 with
// immediate offsets, loop-invariant swizzled base). score = z.e - 0.5||e||^2
// (bias in MFMA C-init); argmax over packed keys (code idx in low 10
// mantissa bits -> v_and_or + v_max).
// NOTE (R7/R12 lesson): no min-waves clamp, no 512-thread blocks — both
// forced VGPR clamps that spilled the pipeline to scratch.
__global__ __launch_bounds__(1024)
void vq_main(const float* __restrict__ z,
             const float* __restrict__ E,
             float* __restrict__ out,
             float* __restrict__ partial) {
    extern __shared__ char smem[];
    unsigned short* sEb = (unsigned short*)smem;           // 128 KB swizzled
    float (*sBiasT)[68] = (float(*)[68])(smem + 131072);   // [16][68] padded

    const int lane = threadIdx.x & 63;
    const int wave = threadIdx.x >> 6;   // 0..15
    const int lrow = lane & 15;          // row/code-col within 16-tile
    const int lgrp = lane >> 4;          // k-group 0..3

    const int n0 = blockIdx.x * 512 + wave * 32;  // wave's first flat row
    const int b  = n0 >> 12;
    const int hw = n0 & 4095;            // 32-aligned; +31 stays in batch
    const float* zb   = z   + (size_t)b * (CDIM * HWDIM);
    float*       outb = out + (size_t)b * (CDIM * HWDIM);

    // ---- fused prep+stage: thread t owns code t (exactly 1024 threads).
    // fp32 -> bf16 convert, swizzled ds_write; bias = -0.5 * sum e^2.
    {
        const int t = threadIdx.x;
        const float4* ev = (const float4*)(E + t * CDIM);
        float s = 0.f;
        #pragma unroll
        for (int k = 0; k < 8; ++k) {
            float4 va = ev[2 * k], vb = ev[2 * k + 1];
            s = fmaf(va.x, va.x, s); s = fmaf(va.y, va.y, s);
            s = fmaf(va.z, va.z, s); s = fmaf(va.w, va.w, s);
            s = fmaf(vb.x, vb.x, s); s = fmaf(vb.y, vb.y, s);
            s = fmaf(vb.z, vb.z, s); s = fmaf(vb.w, vb.w, s);
            bf16x8 w;
            w[0] = (short)f2bf(va.x); w[1] = (short)f2bf(va.y);
            w[2] = (short)f2bf(va.z); w[3] = (short)f2bf(va.w);
            w[4] = (short)f2bf(vb.x); w[5] = (short)f2bf(vb.y);
            w[6] = (short)f2bf(vb.z); w[7] = (short)f2bf(vb.w);
            *(bf16x8*)((char*)sEb + t * 128 + ((k ^ (t & 7)) << 4)) = w;
        }
        sBiasT[t & 15][t >> 4] = -0.5f * s;
    }

    // A fragments: tile t rows n0+16t..+15. lane holds A[lrow][k=32s+8g+j].
    float szz = 0.f;
    bf16x8 afrag[2][2];
    #pragma unroll
    for (int t = 0; t < 2; ++t)
        #pragma unroll
        for (int s = 0; s < 2; ++s)
            #pragma unroll
            for (int j = 0; j < 8; ++j) {
                int c = 32 * s + 8 * lgrp + j;
                float v = zb[c * HWDIM + hw + t * 16 + lrow];
                szz = fmaf(v, v, szz);
                afrag[t][s][j] = (short)f2bf(v);
            }

    float run[2][4];
    #pragma unroll
    for (int t = 0; t < 2; ++t)
        #pragma unroll
        for (int r = 0; r < 4; ++r) run[t][r] = -3.0e38f;

    __syncthreads();   // the ONLY barrier: staged codebook + bias complete

    // loop-invariant swizzled addresses (rowh&7 == lrow&7 for all kt)
    const int s0byte = (lgrp ^ (lrow & 7)) << 4;
    const char* pa = (const char*)sEb + lrow * 128 + s0byte;
    const char* pb = (const char*)sEb + lrow * 128 + (s0byte ^ 64);
    const float* pbias = &sBiasT[lrow][0];
    unsigned codev = (unsigned)lrow;

    for (int ch = 0; ch < 8; ++ch) {
        f32x4 bq0 = *(const f32x4*)(pbias);       // biases kt = ch*8+0..3
        f32x4 bq1 = *(const f32x4*)(pbias + 4);   // biases kt = ch*8+4..7
        #pragma unroll
        for (int j = 0; j < 8; ++j) {
            bf16x8 b0 = *(const bf16x8*)(pa + j * 2048);
            bf16x8 b1 = *(const bf16x8*)(pb + j * 2048);
            const float bv = (j < 4) ? bq0[j] : bq1[j - 4];   // static idx
            f32x4 ci = {bv, bv, bv, bv};
            f32x4 a0 = __builtin_amdgcn_mfma_f32_16x16x32_bf16(afrag[0][0], b0, ci, 0, 0, 0);
            a0 = __builtin_amdgcn_mfma_f32_16x16x32_bf16(afrag[0][1], b1, a0, 0, 0, 0);
            f32x4 a1 = __builtin_amdgcn_mfma_f32_16x16x32_bf16(afrag[1][0], b0, ci, 0, 0, 0);
            a1 = __builtin_amdgcn_mfma_f32_16x16x32_bf16(afrag[1][1], b1, a1, 0, 0, 0);
            const unsigned code = codev + (unsigned)(j * 16);
            #pragma unroll
            for (int r = 0; r < 4; ++r) {
                float k0 = asf((asu(a0[r]) & 0xFFFFFC00u) | code);
                run[0][r] = fmaxf(run[0][r], k0);
                float k1 = asf((asu(a1[r]) & 0xFFFFFC00u) | code);
                run[1][r] = fmaxf(run[1][r], k1);
            }
        }
        pa += 16384; pb += 16384; pbias += 8; codev += 128;
    }

    // reduce packed keys across the 16 code-columns (lrow lanes): pure max
    #pragma unroll
    for (int m = 1; m <= 8; m <<= 1)
        #pragma unroll
        for (int t = 0; t < 2; ++t)
            #pragma unroll
            for (int r = 0; r < 4; ++r)
                run[t][r] = fmaxf(run[t][r], __shfl_xor(run[t][r], m, 64));

    // redistribute winners via shuffles: lane (lrow,lgrp) holds rows 4g+r;
    // epilogue thread needs row lrow of each tile.
    int idxe[2];
    #pragma unroll
    for (int t = 0; t < 2; ++t) {
        const int src = (lrow >> 2) << 4;   // a lane whose lgrp == lrow>>2
        float g0 = __shfl(run[t][0], src, 64);
        float g1 = __shfl(run[t][1], src, 64);
        float g2 = __shfl(run[t][2], src, 64);
        float g3 = __shfl(run[t][3], src, 64);
        float sel = (lrow & 2) ? ((lrow & 1) ? g3 : g2)
                               : ((lrow & 1) ? g1 : g0);
        idxe[t] = (int)(asu(sel) & 1023u);
    }

    // epilogue: gather fp32 codebook rows, write transposed out
    #pragma unroll
    for (int t = 0; t < 2; ++t) {
        const int idxr = idxe[t];
        const f32x4* ep  = (const f32x4*)(E + idxr * CDIM      + 8 * lgrp);
        const f32x4* ep2 = (const f32x4*)(E + idxr * CDIM + 32 + 8 * lgrp);
        f32x4 qa = ep[0], qb = ep[1], qc = ep2[0], qd = ep2[1];
        float* ob = outb + hw + t * 16 + lrow;
        #pragma unroll
        for (int j = 0; j < 4; ++j) {
            ob[(8 * lgrp + j)          * HWDIM] = qa[j];
            ob[(8 * lgrp + 4 + j)      * HWDIM] = qb[j];
            ob[(32 + 8 * lgrp + j)     * HWDIM] = qc[j];
            ob[(32 + 8 * lgrp + 4 + j) * HWDIM] = qd[j];
        }
    }

    // loss partial: sum z^2 + sum over rows of d_min (= -2 * packed score)
    float dsum = 0.f;
    #pragma unroll
    for (int t = 0; t < 2; ++t)
        #pragma unroll
        for (int r = 0; r < 4; ++r) dsum += run[t][r];
    float contrib = szz + ((lrow == 0) ? (-2.f * dsum) : 0.f);
    #pragma unroll
    for (int m = 32; m >= 1; m >>= 1) contrib += __shfl_xor(contrib, m, 64);
    if (lane == 0) partial[blockIdx.x * 16 + wave] = contrib;
}

__global__ void vq_fin(const float* __restrict__ partial,
                       float* __restrict__ out) {
    __shared__ float red[4];
    const int tid = threadIdx.x;   // 256 threads
    float s = 0.f;
    #pragma unroll
    for (int i = 0; i < NPART / 256; ++i) s += partial[i * 256 + tid];
    #pragma unroll
    for (int m = 32; m >= 1; m >>= 1) s += __shfl_xor(s, m, 64);
    if ((tid & 63) == 0) red[tid >> 6] = s;
    __syncthreads();
    if (tid == 0)
        out[NELEM] = 1.25f * (red[0] + red[1] + red[2] + red[3]) / (float)NELEM;
}

extern "C" void kernel_launch(void* const* d_in, const int* in_sizes, int n_in,
                              void* d_out, int out_size, void* d_ws, size_t ws_size,
                              hipStream_t stream) {
    const float* z = (const float*)d_in[0];
    const float* E = (const float*)d_in[1];
    float* out = (float*)d_out;
    float* partial = (float*)d_ws;   // 16 KB

    // allow >64 KB dynamic LDS (host-side attribute; graph-capture safe)
    hipFuncSetAttribute((const void*)vq_main,
                        hipFuncAttributeMaxDynamicSharedMemorySize, LDSSZ);

    vq_main<<<NBLOCK, 1024, LDSSZ, stream>>>(z, E, out, partial);
    vq_fin<<<1, 256, 0, stream>>>(partial, out);
}